// Round 1
// baseline (17771.661 us; speedup 1.0000x reference)
//
#include <hip/hip_runtime.h>
#include <hip/hip_bf16.h>
#include <math.h>

#define Bsz 1024
#define Nn  11
#define Ff  512
#define Zi  10
#define G3  1536   // 3*F for GRU gates

// ---------------------------------------------------------------------------
// init: col[b,f] = nf[b, Zi, f]
// ---------------------------------------------------------------------------
__global__ void init_col_kernel(const float* __restrict__ nf, float* __restrict__ col) {
    int idx = blockIdx.x * 256 + threadIdx.x;       // b*512 + f
    int b = idx >> 9, f = idx & 511;
    col[idx] = nf[(b * Nn + Zi) * Ff + f];
}

// ---------------------------------------------------------------------------
// link MLP: for 11 pairs (i,j) per block, compute
//   adj[b,i,j] = w_out . relu(W2 relu(W1 (x_i*x_j) + b1) + b2) + b_out
// mode 0: full upper-triangular pairs, blockIdx.x = pair-block (6 blocks of 11)
// mode 1: pairs (i, Zi), i = 0..10, single block
// ---------------------------------------------------------------------------
__global__ __launch_bounds__(256) void link_kernel(
    const float* __restrict__ nf, const float* __restrict__ col,
    const float* __restrict__ W1, const float* __restrict__ b1,
    const float* __restrict__ W2, const float* __restrict__ b2,
    const float* __restrict__ w_out, const float* __restrict__ b_out,
    float* __restrict__ adj, int mode)
{
    __shared__ float eb[Nn][Ff];
    __shared__ float hb[Nn][Ff];
    __shared__ const float* uptr[Nn];
    __shared__ const float* vptr[Nn];
    __shared__ int pii[Nn], pjj[Nn];

    const int blk = blockIdx.x;
    const int b   = blockIdx.y;
    const int tid = threadIdx.x;
    const int gt  = tid & 63;   // 64 g-lanes (== lane id; wave index == pt)
    const int pt  = tid >> 6;   // 4 waves

    if (tid < Nn) {
        int i, j;
        if (mode == 0) {
            int q = blk * Nn + tid;       // global pair index 0..65, i<=j
            int r = q; i = 0;
            while (r >= Nn - i) { r -= Nn - i; ++i; }
            j = i + r;
        } else { i = tid; j = Zi; }
        pii[tid] = i; pjj[tid] = j;
        uptr[tid] = (i == Zi) ? (col + b * Ff) : (nf + (b * Nn + i) * Ff);
        vptr[tid] = (j == Zi) ? (col + b * Ff) : (nf + (b * Nn + j) * Ff);
    }
    __syncthreads();

    // e[p][f] = u[f]*v[f]
    for (int idx = tid; idx < Nn * Ff; idx += 256) {
        int p = idx >> 9, f = idx & 511;
        eb[p][f] = uptr[p][f] * vptr[p][f];
    }
    __syncthreads();

    // ---- layer 1: hb = relu(W1 @ eb + b1) ----
    {
        float acc[3][8] = {{0.f}};
        int p0 = (pt     < Nn) ? pt     : Nn - 1;
        int p1 = (pt + 4 < Nn) ? pt + 4 : Nn - 1;
        int p2 = (pt + 8 < Nn) ? pt + 8 : Nn - 1;
        for (int k = 0; k < Ff; k += 4) {
            float4 e0 = *(const float4*)&eb[p0][k];
            float4 e1 = *(const float4*)&eb[p1][k];
            float4 e2 = *(const float4*)&eb[p2][k];
#pragma unroll
            for (int gb = 0; gb < 8; ++gb) {
                const float4 w = *(const float4*)&W1[(gt + 64 * gb) * Ff + k];
                acc[0][gb] += w.x * e0.x + w.y * e0.y + w.z * e0.z + w.w * e0.w;
                acc[1][gb] += w.x * e1.x + w.y * e1.y + w.z * e1.z + w.w * e1.w;
                acc[2][gb] += w.x * e2.x + w.y * e2.y + w.z * e2.z + w.w * e2.w;
            }
        }
#pragma unroll
        for (int gb = 0; gb < 8; ++gb) {
            int g = gt + 64 * gb;
            float bias = b1[g];
#pragma unroll
            for (int pb = 0; pb < 3; ++pb) {
                int p = pt + 4 * pb;
                if (p < Nn) hb[p][g] = fmaxf(acc[pb][gb] + bias, 0.f);
            }
        }
    }
    __syncthreads();

    // ---- layer 2: eb = relu(W2 @ hb + b2) ----
    {
        float acc[3][8] = {{0.f}};
        int p0 = (pt     < Nn) ? pt     : Nn - 1;
        int p1 = (pt + 4 < Nn) ? pt + 4 : Nn - 1;
        int p2 = (pt + 8 < Nn) ? pt + 8 : Nn - 1;
        for (int k = 0; k < Ff; k += 4) {
            float4 e0 = *(const float4*)&hb[p0][k];
            float4 e1 = *(const float4*)&hb[p1][k];
            float4 e2 = *(const float4*)&hb[p2][k];
#pragma unroll
            for (int gb = 0; gb < 8; ++gb) {
                const float4 w = *(const float4*)&W2[(gt + 64 * gb) * Ff + k];
                acc[0][gb] += w.x * e0.x + w.y * e0.y + w.z * e0.z + w.w * e0.w;
                acc[1][gb] += w.x * e1.x + w.y * e1.y + w.z * e1.z + w.w * e1.w;
                acc[2][gb] += w.x * e2.x + w.y * e2.y + w.z * e2.z + w.w * e2.w;
            }
        }
        __syncthreads();   // everyone done reading hb before overwriting eb? (eb!=hb, safe; barrier for store/read ordering below)
#pragma unroll
        for (int gb = 0; gb < 8; ++gb) {
            int g = gt + 64 * gb;
            float bias = b2[g];
#pragma unroll
            for (int pb = 0; pb < 3; ++pb) {
                int p = pt + 4 * pb;
                if (p < Nn) eb[p][g] = fmaxf(acc[pb][gb] + bias, 0.f);
            }
        }
    }
    __syncthreads();

    // ---- reduce: adj[b,i,j] = eb[p] . w_out + b_out (one wave per p-slot) ----
    const float bO = b_out[0];
#pragma unroll
    for (int pb = 0; pb < 3; ++pb) {
        int p = pt + 4 * pb;
        if (p >= Nn) continue;
        float partial = 0.f;
#pragma unroll
        for (int gb = 0; gb < 8; ++gb) {
            int g = gt + 64 * gb;
            partial += eb[p][g] * w_out[g];
        }
        for (int off = 32; off > 0; off >>= 1)
            partial += __shfl_xor(partial, off);
        if (gt == 0) {
            int i = pii[p], j = pjj[p];
            float val = partial + bO;
            adj[b * (Nn * Nn) + i * Nn + j] = val;
            if (i != j) adj[b * (Nn * Nn) + j * Nn + i] = val;
        }
    }
}

// ---------------------------------------------------------------------------
// softmax of adj row Zi -> a_z[b, 0..10]
// ---------------------------------------------------------------------------
__global__ void softmax_az_kernel(const float* __restrict__ adj, float* __restrict__ a_z) {
    int b = blockIdx.x * 256 + threadIdx.x;
    if (b >= Bsz) return;
    const float* row = adj + b * (Nn * Nn) + Zi * Nn;
    float mx = row[0];
#pragma unroll
    for (int j = 1; j < Nn; ++j) mx = fmaxf(mx, row[j]);
    float e[Nn]; float s = 0.f;
#pragma unroll
    for (int j = 0; j < Nn; ++j) { e[j] = expf(row[j] - mx); s += e[j]; }
    float inv = 1.f / s;
#pragma unroll
    for (int j = 0; j < Nn; ++j) a_z[b * Nn + j] = e[j] * inv;
}

// ---------------------------------------------------------------------------
// m_fix[b,f] = sum_{j<10} a_z[b,j] * nf[b,j,f]
// ---------------------------------------------------------------------------
__global__ void mfix_kernel(const float* __restrict__ nf, const float* __restrict__ a_z,
                            float* __restrict__ m_fix) {
    int idx = blockIdx.x * 256 + threadIdx.x;
    int b = idx >> 9, f = idx & 511;
    float s = 0.f;
#pragma unroll
    for (int j = 0; j < Nn - 1; ++j)
        s += a_z[b * Nn + j] * nf[(b * Nn + j) * Ff + f];
    m_fix[idx] = s;
}

// m_z = m_fix + a_z[b,Zi] * col
__global__ void mz_kernel(const float* __restrict__ m_fix, const float* __restrict__ a_z,
                          const float* __restrict__ col, float* __restrict__ m_z) {
    int idx = blockIdx.x * 256 + threadIdx.x;
    int b = idx >> 9;
    m_z[idx] = m_fix[idx] + a_z[b * Nn + Zi] * col[idx];
}

// ---------------------------------------------------------------------------
// batched gemv: C[b,g] = sum_f A[b,f] * W[g,f];  16 b-rows x 256 g-cols per wg
// ---------------------------------------------------------------------------
__global__ __launch_bounds__(256) void gemv_kernel(const float* __restrict__ A,
                                                   const float* __restrict__ W,
                                                   float* __restrict__ C, int Gtot) {
    __shared__ float Ab[16][Ff];
    const int gblk = blockIdx.x;
    const int bblk = blockIdx.y;
    const int tid  = threadIdx.x;
    for (int idx = tid; idx < 16 * Ff; idx += 256) {
        int p = idx >> 9, f = idx & 511;
        Ab[p][f] = A[(bblk * 16 + p) * Ff + f];
    }
    __syncthreads();
    const int gt = tid & 63, pt = tid >> 6;
    float acc[4][4] = {{0.f}};
    const int g0 = gblk * 256;
    for (int k = 0; k < Ff; k += 4) {
        float4 a0 = *(const float4*)&Ab[pt][k];
        float4 a1 = *(const float4*)&Ab[pt + 4][k];
        float4 a2 = *(const float4*)&Ab[pt + 8][k];
        float4 a3 = *(const float4*)&Ab[pt + 12][k];
#pragma unroll
        for (int gb = 0; gb < 4; ++gb) {
            const float4 w = *(const float4*)&W[(g0 + gt + 64 * gb) * Ff + k];
            acc[0][gb] += w.x * a0.x + w.y * a0.y + w.z * a0.z + w.w * a0.w;
            acc[1][gb] += w.x * a1.x + w.y * a1.y + w.z * a1.z + w.w * a1.w;
            acc[2][gb] += w.x * a2.x + w.y * a2.y + w.z * a2.z + w.w * a2.w;
            acc[3][gb] += w.x * a3.x + w.y * a3.y + w.z * a3.z + w.w * a3.w;
        }
    }
#pragma unroll
    for (int pb = 0; pb < 4; ++pb)
#pragma unroll
        for (int gb = 0; gb < 4; ++gb)
            C[(bblk * 16 + pt + 4 * pb) * Gtot + g0 + gt + 64 * gb] = acc[pb][gb];
}

// ---------------------------------------------------------------------------
// GRU pointwise: col = (1-z)*n + z*col
// ---------------------------------------------------------------------------
__global__ void gru_kernel(const float* __restrict__ gi, const float* __restrict__ gh,
                           float* __restrict__ col) {
    int idx = blockIdx.x * 256 + threadIdx.x;
    int b = idx >> 9, f = idx & 511;
    const float* gib = gi + b * G3;
    const float* ghb = gh + b * G3;
    float ir = gib[f], iz = gib[Ff + f], in = gib[2 * Ff + f];
    float hr = ghb[f], hz = ghb[Ff + f], hn = ghb[2 * Ff + f];
    float r = 1.f / (1.f + expf(-(ir + hr)));
    float z = 1.f / (1.f + expf(-(iz + hz)));
    float n = tanhf(in + r * hn);
    float h = col[idx];
    col[idx] = (1.f - z) * n + z * h;
}

// ---------------------------------------------------------------------------
extern "C" void kernel_launch(void* const* d_in, const int* in_sizes, int n_in,
                              void* d_out, int out_size, void* d_ws, size_t ws_size,
                              hipStream_t stream) {
    const float* nf    = (const float*)d_in[0];
    const float* W1    = (const float*)d_in[1];
    const float* b1    = (const float*)d_in[2];
    const float* W2    = (const float*)d_in[3];
    const float* b2    = (const float*)d_in[4];
    const float* w_out = (const float*)d_in[5];
    const float* b_out = (const float*)d_in[6];
    const float* W_ih  = (const float*)d_in[7];
    const float* W_hh  = (const float*)d_in[8];

    float* adj = (float*)d_out;                 // (B, 11, 11)
    float* col = adj + Bsz * Nn * Nn;           // (B, 512) — working col, also final output

    float* ws    = (float*)d_ws;
    float* a_z   = ws;                          // B*11 (use 16384 slot)
    float* m_fix = ws + 16384;                  // B*512
    float* m_z   = m_fix + Bsz * Ff;            // B*512
    float* gi    = m_z + Bsz * Ff;              // B*1536
    float* gh    = gi + Bsz * G3;               // B*1536

    init_col_kernel<<<(Bsz * Ff) / 256, 256, 0, stream>>>(nf, col);

    for (int t = 0; t < 3; ++t) {
        if (t == 0)
            link_kernel<<<dim3(6, Bsz), 256, 0, stream>>>(nf, col, W1, b1, W2, b2,
                                                          w_out, b_out, adj, 0);
        else
            link_kernel<<<dim3(1, Bsz), 256, 0, stream>>>(nf, col, W1, b1, W2, b2,
                                                          w_out, b_out, adj, 1);
        softmax_az_kernel<<<Bsz / 256, 256, 0, stream>>>(adj, a_z);
        mfix_kernel<<<(Bsz * Ff) / 256, 256, 0, stream>>>(nf, a_z, m_fix);

        for (int s = 0; s < 3; ++s) {
            mz_kernel<<<(Bsz * Ff) / 256, 256, 0, stream>>>(m_fix, a_z, col, m_z);
            gemv_kernel<<<dim3(G3 / 256, Bsz / 16), 256, 0, stream>>>(m_z, W_ih, gi, G3);
            gemv_kernel<<<dim3(G3 / 256, Bsz / 16), 256, 0, stream>>>(col, W_hh, gh, G3);
            gru_kernel<<<(Bsz * Ff) / 256, 256, 0, stream>>>(gi, gh, col);
        }
    }
}

// Round 2
// 2946.011 us; speedup vs baseline: 6.0324x; 6.0324x over previous
//
#include <hip/hip_runtime.h>
#include <hip/hip_bf16.h>
#include <math.h>

#define Bsz 1024
#define Nn  11
#define Ff  512
#define Zi  10
#define G3  1536   // 3*F for GRU gates

typedef __attribute__((ext_vector_type(8))) short bfrag;   // 8 bf16 (4 VGPRs)
typedef __attribute__((ext_vector_type(4))) float facc;    // 4 fp32 acc

__device__ __forceinline__ float bf2f(short u) {
    union { unsigned int i; float f; } v;
    v.i = ((unsigned int)(unsigned short)u) << 16;
    return v.f;
}
__device__ __forceinline__ unsigned short f2bf(float f) {
    __hip_bfloat16 h = __float2bfloat16(f);
    return *reinterpret_cast<unsigned short*>(&h);
}

// ---------------------------------------------------------------------------
// init: col[b,f] = nf[b, Zi, f]
// ---------------------------------------------------------------------------
__global__ void init_col_kernel(const float* __restrict__ nf, float* __restrict__ col) {
    int idx = blockIdx.x * 256 + threadIdx.x;
    int b = idx >> 9, f = idx & 511;
    col[idx] = nf[(b * Nn + Zi) * Ff + f];
}

// ---------------------------------------------------------------------------
// fp32 -> bf16 conversion (for W1, W2)
// ---------------------------------------------------------------------------
__global__ void convert_bf16_kernel(const float* __restrict__ src,
                                    unsigned short* __restrict__ dst) {
    int i = blockIdx.x * 256 + threadIdx.x;
    dst[i] = f2bf(src[i]);
}

// ---------------------------------------------------------------------------
// link MLP via MFMA. Block = 64 rows (1 pair x 64 batches), 512 threads.
// Sbuf [64][512] bf16, XOR-swizzled, reused in-place across layers.
// mode 0: p = blockIdx.x>>4 is triangular pair index (66 pairs)
// mode 1: p = i, pair (i, Zi) (11 pairs)
// ---------------------------------------------------------------------------
__global__ __launch_bounds__(512) void link_mfma_kernel(
    const float* __restrict__ nf, const float* __restrict__ col,
    const unsigned short* __restrict__ W1bf, const float* __restrict__ b1,
    const unsigned short* __restrict__ W2bf, const float* __restrict__ b2,
    const float* __restrict__ w_out, const float* __restrict__ b_out,
    float* __restrict__ adj, int mode)
{
    __shared__ unsigned short Sbuf[64 * 512];   // 64 KiB

    const int pb  = blockIdx.x;
    const int tid = threadIdx.x;
    const int p   = pb >> 4;      // pair index (uniform in block)

    int pi, pj;
    if (mode == 0) {
        int r = p, i = 0;
        while (r >= Nn - i) { r -= Nn - i; ++i; }
        pi = i; pj = i + r;
    } else { pi = p; pj = Zi; }

    // ---- E build: Sbuf[r][f] = bf16(x_i[f] * x_j[f]) ----
    {
        const int r  = tid >> 3;          // row 0..63
        const int fc = tid & 7;           // f-chunk 0..7 (64 f each)
        const int b  = ((pb & 15) << 6) + r;
        const float* xi = (pi == Zi) ? (col + b * Ff) : (nf + (b * Nn + pi) * Ff);
        const float* xj = (pj == Zi) ? (col + b * Ff) : (nf + (b * Nn + pj) * Ff);
        const unsigned sw = ((unsigned)(r & 7)) << 4;
#pragma unroll
        for (int w = 0; w < 8; ++w) {
            int ff = fc * 64 + w * 8;
            float4 u0 = *(const float4*)(xi + ff);
            float4 u1 = *(const float4*)(xi + ff + 4);
            float4 v0 = *(const float4*)(xj + ff);
            float4 v1 = *(const float4*)(xj + ff + 4);
            uint4 pk;
            pk.x = (unsigned)f2bf(u0.x * v0.x) | ((unsigned)f2bf(u0.y * v0.y) << 16);
            pk.y = (unsigned)f2bf(u0.z * v0.z) | ((unsigned)f2bf(u0.w * v0.w) << 16);
            pk.z = (unsigned)f2bf(u1.x * v1.x) | ((unsigned)f2bf(u1.y * v1.y) << 16);
            pk.w = (unsigned)f2bf(u1.z * v1.z) | ((unsigned)f2bf(u1.w * v1.w) << 16);
            unsigned byte = ((unsigned)(r * 1024 + ff * 2)) ^ sw;
            *(uint4*)((char*)Sbuf + byte) = pk;
        }
    }
    __syncthreads();

    // ---- 2 MLP layers, in-place in Sbuf ----
    const int wid  = tid >> 6;
    const int lane = tid & 63;
    const int mh = wid >> 2;      // M-half 0..1 (rows mh*32 .. +32)
    const int nq = wid & 3;       // N-quarter 0..3 (cols nq*128 .. +128)
    const int lr = lane & 15;
    const int lk = lane >> 4;

    facc acc[2][8];

#pragma unroll 1
    for (int layer = 0; layer < 2; ++layer) {
        const unsigned short* W = layer ? W2bf : W1bf;
        const float* bias = layer ? b2 : b1;
#pragma unroll
        for (int ms = 0; ms < 2; ++ms)
#pragma unroll
            for (int nt = 0; nt < 8; ++nt)
                acc[ms][nt] = (facc){0.f, 0.f, 0.f, 0.f};

        for (int k0 = 0; k0 < Ff; k0 += 32) {
            const int kk = k0 + lk * 8;
            bfrag a0, a1;
            {
                int row = mh * 32 + lr;
                unsigned byte = ((unsigned)(row * 1024 + kk * 2)) ^ (((unsigned)(row & 7)) << 4);
                a0 = *(const bfrag*)((const char*)Sbuf + byte);
                row += 16;
                byte = ((unsigned)(row * 1024 + kk * 2)) ^ (((unsigned)(row & 7)) << 4);
                a1 = *(const bfrag*)((const char*)Sbuf + byte);
            }
#pragma unroll
            for (int nt = 0; nt < 8; ++nt) {
                int g = nq * 128 + nt * 16 + lr;
                bfrag bf_ = *(const bfrag*)(W + g * Ff + kk);
                acc[0][nt] = __builtin_amdgcn_mfma_f32_16x16x32_bf16(a0, bf_, acc[0][nt], 0, 0, 0);
                acc[1][nt] = __builtin_amdgcn_mfma_f32_16x16x32_bf16(a1, bf_, acc[1][nt], 0, 0, 0);
            }
        }
        __syncthreads();   // all K-reads of Sbuf complete before overwrite

        // epilogue: bias + relu -> bf16, back into Sbuf (swizzled)
#pragma unroll
        for (int nt = 0; nt < 8; ++nt) {
            int colg = nq * 128 + nt * 16 + lr;
            float bv = bias[colg];
#pragma unroll
            for (int ms = 0; ms < 2; ++ms) {
#pragma unroll
                for (int reg = 0; reg < 4; ++reg) {
                    int row = mh * 32 + ms * 16 + lk * 4 + reg;
                    float v = fmaxf(acc[ms][nt][reg] + bv, 0.f);
                    unsigned byte = ((unsigned)(row * 1024 + colg * 2)) ^ (((unsigned)(row & 7)) << 4);
                    *(unsigned short*)((char*)Sbuf + byte) = f2bf(v);
                }
            }
        }
        __syncthreads();
    }

    // ---- final dot with w_out ----
    {
        const int r  = tid >> 3;
        const int fc = tid & 7;
        const unsigned sw = ((unsigned)(r & 7)) << 4;
        float partial = 0.f;
#pragma unroll
        for (int w = 0; w < 8; ++w) {
            int ff = fc * 64 + w * 8;
            unsigned byte = ((unsigned)(r * 1024 + ff * 2)) ^ sw;
            bfrag h8 = *(const bfrag*)((const char*)Sbuf + byte);
            float4 w0 = *(const float4*)(w_out + ff);
            float4 w1 = *(const float4*)(w_out + ff + 4);
            partial += bf2f(h8[0]) * w0.x + bf2f(h8[1]) * w0.y
                     + bf2f(h8[2]) * w0.z + bf2f(h8[3]) * w0.w
                     + bf2f(h8[4]) * w1.x + bf2f(h8[5]) * w1.y
                     + bf2f(h8[6]) * w1.z + bf2f(h8[7]) * w1.w;
        }
        partial += __shfl_xor(partial, 1);
        partial += __shfl_xor(partial, 2);
        partial += __shfl_xor(partial, 4);
        if (fc == 0) {
            int b = ((pb & 15) << 6) + r;
            float val = partial + b_out[0];
            adj[b * (Nn * Nn) + pi * Nn + pj] = val;
            if (pi != pj) adj[b * (Nn * Nn) + pj * Nn + pi] = val;
        }
    }
}

// ---------------------------------------------------------------------------
// softmax of adj row Zi -> a_z[b, 0..10]
// ---------------------------------------------------------------------------
__global__ void softmax_az_kernel(const float* __restrict__ adj, float* __restrict__ a_z) {
    int b = blockIdx.x * 256 + threadIdx.x;
    if (b >= Bsz) return;
    const float* row = adj + b * (Nn * Nn) + Zi * Nn;
    float mx = row[0];
#pragma unroll
    for (int j = 1; j < Nn; ++j) mx = fmaxf(mx, row[j]);
    float e[Nn]; float s = 0.f;
#pragma unroll
    for (int j = 0; j < Nn; ++j) { e[j] = expf(row[j] - mx); s += e[j]; }
    float inv = 1.f / s;
#pragma unroll
    for (int j = 0; j < Nn; ++j) a_z[b * Nn + j] = e[j] * inv;
}

// ---------------------------------------------------------------------------
// m_fix[b,f] = sum_{j<10} a_z[b,j] * nf[b,j,f]
// ---------------------------------------------------------------------------
__global__ void mfix_kernel(const float* __restrict__ nf, const float* __restrict__ a_z,
                            float* __restrict__ m_fix) {
    int idx = blockIdx.x * 256 + threadIdx.x;
    int b = idx >> 9, f = idx & 511;
    float s = 0.f;
#pragma unroll
    for (int j = 0; j < Nn - 1; ++j)
        s += a_z[b * Nn + j] * nf[(b * Nn + j) * Ff + f];
    m_fix[idx] = s;
}

// m_z = m_fix + a_z[b,Zi] * col
__global__ void mz_kernel(const float* __restrict__ m_fix, const float* __restrict__ a_z,
                          const float* __restrict__ col, float* __restrict__ m_z) {
    int idx = blockIdx.x * 256 + threadIdx.x;
    int b = idx >> 9;
    m_z[idx] = m_fix[idx] + a_z[b * Nn + Zi] * col[idx];
}

// ---------------------------------------------------------------------------
// batched gemv: C[b,g] = sum_f A[b,f] * W[g,f];  16 b-rows x 256 g-cols per wg
// ---------------------------------------------------------------------------
__global__ __launch_bounds__(256) void gemv_kernel(const float* __restrict__ A,
                                                   const float* __restrict__ W,
                                                   float* __restrict__ C, int Gtot) {
    __shared__ float Ab[16][Ff];
    const int gblk = blockIdx.x;
    const int bblk = blockIdx.y;
    const int tid  = threadIdx.x;
    for (int idx = tid; idx < 16 * Ff; idx += 256) {
        int pp = idx >> 9, f = idx & 511;
        Ab[pp][f] = A[(bblk * 16 + pp) * Ff + f];
    }
    __syncthreads();
    const int gt = tid & 63, pt = tid >> 6;
    float acc[4][4] = {{0.f}};
    const int g0 = gblk * 256;
    for (int k = 0; k < Ff; k += 4) {
        float4 a0 = *(const float4*)&Ab[pt][k];
        float4 a1 = *(const float4*)&Ab[pt + 4][k];
        float4 a2 = *(const float4*)&Ab[pt + 8][k];
        float4 a3 = *(const float4*)&Ab[pt + 12][k];
#pragma unroll
        for (int gb = 0; gb < 4; ++gb) {
            const float4 w = *(const float4*)&W[(g0 + gt + 64 * gb) * Ff + k];
            acc[0][gb] += w.x * a0.x + w.y * a0.y + w.z * a0.z + w.w * a0.w;
            acc[1][gb] += w.x * a1.x + w.y * a1.y + w.z * a1.z + w.w * a1.w;
            acc[2][gb] += w.x * a2.x + w.y * a2.y + w.z * a2.z + w.w * a2.w;
            acc[3][gb] += w.x * a3.x + w.y * a3.y + w.z * a3.z + w.w * a3.w;
        }
    }
#pragma unroll
    for (int pbv = 0; pbv < 4; ++pbv)
#pragma unroll
        for (int gb = 0; gb < 4; ++gb)
            C[(bblk * 16 + pt + 4 * pbv) * Gtot + g0 + gt + 64 * gb] = acc[pbv][gb];
}

// ---------------------------------------------------------------------------
// GRU pointwise: col = (1-z)*n + z*col
// ---------------------------------------------------------------------------
__global__ void gru_kernel(const float* __restrict__ gi, const float* __restrict__ gh,
                           float* __restrict__ col) {
    int idx = blockIdx.x * 256 + threadIdx.x;
    int b = idx >> 9, f = idx & 511;
    const float* gib = gi + b * G3;
    const float* ghb = gh + b * G3;
    float ir = gib[f], iz = gib[Ff + f], in = gib[2 * Ff + f];
    float hr = ghb[f], hz = ghb[Ff + f], hn = ghb[2 * Ff + f];
    float r = 1.f / (1.f + expf(-(ir + hr)));
    float z = 1.f / (1.f + expf(-(iz + hz)));
    float n = tanhf(in + r * hn);
    float h = col[idx];
    col[idx] = (1.f - z) * n + z * h;
}

// ---------------------------------------------------------------------------
extern "C" void kernel_launch(void* const* d_in, const int* in_sizes, int n_in,
                              void* d_out, int out_size, void* d_ws, size_t ws_size,
                              hipStream_t stream) {
    const float* nf    = (const float*)d_in[0];
    const float* W1    = (const float*)d_in[1];
    const float* b1    = (const float*)d_in[2];
    const float* W2    = (const float*)d_in[3];
    const float* b2    = (const float*)d_in[4];
    const float* w_out = (const float*)d_in[5];
    const float* b_out = (const float*)d_in[6];
    const float* W_ih  = (const float*)d_in[7];
    const float* W_hh  = (const float*)d_in[8];

    float* adj = (float*)d_out;                 // (B, 11, 11)
    float* col = adj + Bsz * Nn * Nn;           // (B, 512)

    float* ws    = (float*)d_ws;
    float* a_z   = ws;                          // B*11 (16384 slot)
    float* m_fix = ws + 16384;                  // B*512
    float* m_z   = m_fix + Bsz * Ff;            // B*512
    float* gi    = m_z + Bsz * Ff;              // B*1536
    float* gh    = gi + Bsz * G3;               // B*1536
    unsigned short* W1bf = (unsigned short*)(gh + Bsz * G3);  // 512*512 bf16
    unsigned short* W2bf = W1bf + Ff * Ff;

    init_col_kernel<<<(Bsz * Ff) / 256, 256, 0, stream>>>(nf, col);
    convert_bf16_kernel<<<(Ff * Ff) / 256, 256, 0, stream>>>(W1, W1bf);
    convert_bf16_kernel<<<(Ff * Ff) / 256, 256, 0, stream>>>(W2, W2bf);

    for (int t = 0; t < 3; ++t) {
        if (t == 0)
            link_mfma_kernel<<<66 * 16, 512, 0, stream>>>(nf, col, W1bf, b1, W2bf, b2,
                                                          w_out, b_out, adj, 0);
        else
            link_mfma_kernel<<<11 * 16, 512, 0, stream>>>(nf, col, W1bf, b1, W2bf, b2,
                                                          w_out, b_out, adj, 1);
        softmax_az_kernel<<<Bsz / 256, 256, 0, stream>>>(adj, a_z);
        mfix_kernel<<<(Bsz * Ff) / 256, 256, 0, stream>>>(nf, a_z, m_fix);

        for (int s = 0; s < 3; ++s) {
            mz_kernel<<<(Bsz * Ff) / 256, 256, 0, stream>>>(m_fix, a_z, col, m_z);
            gemv_kernel<<<dim3(G3 / 256, Bsz / 16), 256, 0, stream>>>(m_z, W_ih, gi, G3);
            gemv_kernel<<<dim3(G3 / 256, Bsz / 16), 256, 0, stream>>>(col, W_hh, gh, G3);
            gru_kernel<<<(Bsz * Ff) / 256, 256, 0, stream>>>(gi, gh, col);
        }
    }
}

// Round 3
// 588.671 us; speedup vs baseline: 30.1895x; 5.0045x over previous
//
#include <hip/hip_runtime.h>
#include <hip/hip_bf16.h>
#include <math.h>

#define Bsz 1024
#define Nn  11
#define Ff  512
#define Zi  10
#define G3  1536   // 3*F for GRU gates

typedef __attribute__((ext_vector_type(8))) short bfrag;   // 8 bf16 (4 VGPRs)
typedef __attribute__((ext_vector_type(4))) float facc;    // 4 fp32 acc

__device__ __forceinline__ float bf2f(short u) {
    union { unsigned int i; float f; } v;
    v.i = ((unsigned int)(unsigned short)u) << 16;
    return v.f;
}
__device__ __forceinline__ unsigned short f2bf(float f) {
    __hip_bfloat16 h = __float2bfloat16(f);
    return *reinterpret_cast<unsigned short*>(&h);
}

// async global->LDS, 16B per lane; dst must be wave-uniform base (lane*16 added by HW)
__device__ __forceinline__ void gl_lds16(const void* src, void* dst) {
    __builtin_amdgcn_global_load_lds((const __attribute__((address_space(1))) void*)src,
                                     (__attribute__((address_space(3))) void*)dst, 16, 0, 0);
}

// ---------------------------------------------------------------------------
// init: col[b,f] = nf[b, Zi, f]
// ---------------------------------------------------------------------------
__global__ void init_col_kernel(const float* __restrict__ nf, float* __restrict__ col) {
    int idx = blockIdx.x * 256 + threadIdx.x;
    int b = idx >> 9, f = idx & 511;
    col[idx] = nf[(b * Nn + Zi) * Ff + f];
}

// ---------------------------------------------------------------------------
// fp32 -> bf16 conversion (weights)
// ---------------------------------------------------------------------------
__global__ void convert_bf16_kernel(const float* __restrict__ src,
                                    unsigned short* __restrict__ dst) {
    int i = blockIdx.x * 256 + threadIdx.x;
    dst[i] = f2bf(src[i]);
}

// ---------------------------------------------------------------------------
// W K-slice staging into LDS, link version: 512 g-rows x 32 k, 32 KB, 512 thr.
// LDS layout: byte(g,kk) = g*64 + kk*2, value XOR-swizzled: stored[o] =
// W[o ^ ((g&3)<<4)] (bits 4-5 flip only; involution; 16B-granular).
// ---------------------------------------------------------------------------
__device__ __forceinline__ void stage_link(const unsigned short* W, int k0,
                                           unsigned short* buf, int tid) {
    const int w = tid >> 6;
#pragma unroll
    for (int i = 0; i < 4; ++i) {
        int chunk = i * 512 + tid;          // dest 16B-chunk index
        int o = chunk << 4;                 // dest byte offset
        int g = o >> 6;                     // 0..511
        int osrc = o ^ ((g & 3) << 4);
        int kk = (osrc & 63) >> 1;          // 0..31
        gl_lds16(W + g * Ff + k0 * 32 + kk, buf + ((i * 512 + w * 64) << 3));
    }
}

// gates version: 128 g-rows x 32 k, 8 KB, 256 thr
__device__ __forceinline__ void stage_gates(const unsigned short* W, int nb, int k0,
                                            unsigned short* buf, int tid) {
    const int w = tid >> 6;
#pragma unroll
    for (int i = 0; i < 2; ++i) {
        int chunk = i * 256 + tid;
        int o = chunk << 4;
        int g = o >> 6;                     // 0..127 local col
        int osrc = o ^ ((g & 3) << 4);
        int kk = (osrc & 63) >> 1;
        gl_lds16(W + (nb * 128 + g) * Ff + k0 * 32 + kk, buf + ((i * 256 + w * 64) << 3));
    }
}

// ---------------------------------------------------------------------------
// link MLP via MFMA + staged W. Block = 64 rows (1 pair x 64 batches), 512 thr.
// Sbuf [64][512] bf16 swizzled, in-place across layers. Wb: 2x32KB K-slices.
// ---------------------------------------------------------------------------
__global__ __launch_bounds__(512) void link_mfma_kernel(
    const float* __restrict__ nf, const float* __restrict__ col,
    const unsigned short* __restrict__ W1bf, const float* __restrict__ b1,
    const unsigned short* __restrict__ W2bf, const float* __restrict__ b2,
    const float* __restrict__ w_out, const float* __restrict__ b_out,
    float* __restrict__ adj, int mode)
{
    __shared__ unsigned short Sbuf[64 * 512];     // 64 KiB
    __shared__ unsigned short Wb[2][512 * 32];    // 2 x 32 KiB

    const int pb  = blockIdx.x;
    const int tid = threadIdx.x;
    const int p   = pb >> 4;

    int pi, pj;
    if (mode == 0) {
        int r = p, i = 0;
        while (r >= Nn - i) { r -= Nn - i; ++i; }
        pi = i; pj = i + r;
    } else { pi = p; pj = Zi; }

    // ---- E build: Sbuf[r][f] = bf16(x_i[f] * x_j[f]) ----
    {
        const int r  = tid >> 3;
        const int fc = tid & 7;
        const int b  = ((pb & 15) << 6) + r;
        const float* xi = (pi == Zi) ? (col + b * Ff) : (nf + (b * Nn + pi) * Ff);
        const float* xj = (pj == Zi) ? (col + b * Ff) : (nf + (b * Nn + pj) * Ff);
        const unsigned sw = ((unsigned)(r & 7)) << 4;
#pragma unroll
        for (int w = 0; w < 8; ++w) {
            int ff = fc * 64 + w * 8;
            float4 u0 = *(const float4*)(xi + ff);
            float4 u1 = *(const float4*)(xi + ff + 4);
            float4 v0 = *(const float4*)(xj + ff);
            float4 v1 = *(const float4*)(xj + ff + 4);
            uint4 pk;
            pk.x = (unsigned)f2bf(u0.x * v0.x) | ((unsigned)f2bf(u0.y * v0.y) << 16);
            pk.y = (unsigned)f2bf(u0.z * v0.z) | ((unsigned)f2bf(u0.w * v0.w) << 16);
            pk.z = (unsigned)f2bf(u1.x * v1.x) | ((unsigned)f2bf(u1.y * v1.y) << 16);
            pk.w = (unsigned)f2bf(u1.z * v1.z) | ((unsigned)f2bf(u1.w * v1.w) << 16);
            unsigned byte = ((unsigned)(r * 1024 + ff * 2)) ^ sw;
            *(uint4*)((char*)Sbuf + byte) = pk;
        }
    }

    const int wid  = tid >> 6;
    const int lane = tid & 63;
    const int mh = wid >> 2;
    const int nq = wid & 3;
    const int lr = lane & 15;
    const int lk = lane >> 4;

    facc acc[2][8];

#pragma unroll 1
    for (int layer = 0; layer < 2; ++layer) {
        const unsigned short* W = layer ? W2bf : W1bf;
        const float* bias = layer ? b2 : b1;

        stage_link(W, 0, &Wb[0][0], tid);
        __syncthreads();     // drains stage (vmcnt) + covers Sbuf writes

#pragma unroll
        for (int ms = 0; ms < 2; ++ms)
#pragma unroll
            for (int nt = 0; nt < 8; ++nt)
                acc[ms][nt] = (facc){0.f, 0.f, 0.f, 0.f};

#pragma unroll 1
        for (int k0 = 0; k0 < 16; ++k0) {
            if (k0 < 15) stage_link(W, k0 + 1, &Wb[(k0 + 1) & 1][0], tid);
            const char* Wc = (const char*)&Wb[k0 & 1][0];
            const int kk = k0 * 32 + lk * 8;
            bfrag a0, a1;
            {
                int row = mh * 32 + lr;
                unsigned byte = ((unsigned)(row * 1024 + kk * 2)) ^ (((unsigned)(row & 7)) << 4);
                a0 = *(const bfrag*)((const char*)Sbuf + byte);
                row += 16;
                byte = ((unsigned)(row * 1024 + kk * 2)) ^ (((unsigned)(row & 7)) << 4);
                a1 = *(const bfrag*)((const char*)Sbuf + byte);
            }
#pragma unroll
            for (int nt = 0; nt < 8; ++nt) {
                int g = nq * 128 + nt * 16 + lr;
                bfrag bf_ = *(const bfrag*)(Wc + (((unsigned)(g * 64 + lk * 16)) ^ (((unsigned)(g & 3)) << 4)));
                acc[0][nt] = __builtin_amdgcn_mfma_f32_16x16x32_bf16(a0, bf_, acc[0][nt], 0, 0, 0);
                acc[1][nt] = __builtin_amdgcn_mfma_f32_16x16x32_bf16(a1, bf_, acc[1][nt], 0, 0, 0);
            }
            __syncthreads();   // drains this step's stage; ds_reads complete
        }

        // epilogue: bias + relu -> bf16, in-place into Sbuf (swizzled)
#pragma unroll
        for (int nt = 0; nt < 8; ++nt) {
            int colg = nq * 128 + nt * 16 + lr;
            float bv = bias[colg];
#pragma unroll
            for (int ms = 0; ms < 2; ++ms) {
#pragma unroll
                for (int reg = 0; reg < 4; ++reg) {
                    int row = mh * 32 + ms * 16 + lk * 4 + reg;
                    float v = fmaxf(acc[ms][nt][reg] + bv, 0.f);
                    unsigned byte = ((unsigned)(row * 1024 + colg * 2)) ^ (((unsigned)(row & 7)) << 4);
                    *(unsigned short*)((char*)Sbuf + byte) = f2bf(v);
                }
            }
        }
        // next layer's stage+sync (or final sync below) publishes these writes
    }
    __syncthreads();

    // ---- final dot with w_out ----
    {
        const int r  = tid >> 3;
        const int fc = tid & 7;
        const unsigned sw = ((unsigned)(r & 7)) << 4;
        float partial = 0.f;
#pragma unroll
        for (int w = 0; w < 8; ++w) {
            int ff = fc * 64 + w * 8;
            unsigned byte = ((unsigned)(r * 1024 + ff * 2)) ^ sw;
            bfrag h8 = *(const bfrag*)((const char*)Sbuf + byte);
            float4 w0 = *(const float4*)(w_out + ff);
            float4 w1 = *(const float4*)(w_out + ff + 4);
            partial += bf2f(h8[0]) * w0.x + bf2f(h8[1]) * w0.y
                     + bf2f(h8[2]) * w0.z + bf2f(h8[3]) * w0.w
                     + bf2f(h8[4]) * w1.x + bf2f(h8[5]) * w1.y
                     + bf2f(h8[6]) * w1.z + bf2f(h8[7]) * w1.w;
        }
        partial += __shfl_xor(partial, 1);
        partial += __shfl_xor(partial, 2);
        partial += __shfl_xor(partial, 4);
        if (fc == 0) {
            int b = ((pb & 15) << 6) + r;
            float val = partial + b_out[0];
            adj[b * (Nn * Nn) + pi * Nn + pj] = val;
            if (pi != pj) adj[b * (Nn * Nn) + pj * Nn + pi] = val;
        }
    }
}

// ---------------------------------------------------------------------------
// softmax of adj row Zi -> a_z[b, 0..10]
// ---------------------------------------------------------------------------
__global__ void softmax_az_kernel(const float* __restrict__ adj, float* __restrict__ a_z) {
    int b = blockIdx.x * 256 + threadIdx.x;
    if (b >= Bsz) return;
    const float* row = adj + b * (Nn * Nn) + Zi * Nn;
    float mx = row[0];
#pragma unroll
    for (int j = 1; j < Nn; ++j) mx = fmaxf(mx, row[j]);
    float e[Nn]; float s = 0.f;
#pragma unroll
    for (int j = 0; j < Nn; ++j) { e[j] = expf(row[j] - mx); s += e[j]; }
    float inv = 1.f / s;
#pragma unroll
    for (int j = 0; j < Nn; ++j) a_z[b * Nn + j] = e[j] * inv;
}

// ---------------------------------------------------------------------------
// m_fix[b,f] = sum_{j<10} a_z[b,j] * nf[b,j,f]
// ---------------------------------------------------------------------------
__global__ void mfix_kernel(const float* __restrict__ nf, const float* __restrict__ a_z,
                            float* __restrict__ m_fix) {
    int idx = blockIdx.x * 256 + threadIdx.x;
    int b = idx >> 9, f = idx & 511;
    float s = 0.f;
#pragma unroll
    for (int j = 0; j < Nn - 1; ++j)
        s += a_z[b * Nn + j] * nf[(b * Nn + j) * Ff + f];
    m_fix[idx] = s;
}

// ---------------------------------------------------------------------------
// gates GEMM: one dispatch computes gi = mz @ Wih^T AND gh = col @ Whh^T.
// grid (24, 16): xb<12 -> gi (A = m_fix + az*col, built in staging), else gh.
// Block: 64 rows x 128 cols, 256 thr (4 waves = 2M x 2N), staged W slices.
// ---------------------------------------------------------------------------
__global__ __launch_bounds__(256) void gates_kernel(
    const float* __restrict__ m_fix, const float* __restrict__ a_z,
    const float* __restrict__ colp,
    const unsigned short* __restrict__ Wih, const unsigned short* __restrict__ Whh,
    float* __restrict__ gi, float* __restrict__ gh)
{
    __shared__ unsigned short Ab[64 * 512];      // 64 KiB
    __shared__ unsigned short Wb[2][128 * 32];   // 2 x 8 KiB

    const int xb = blockIdx.x, yb = blockIdx.y, tid = threadIdx.x;
    const bool isGi = xb < 12;
    const int nb = isGi ? xb : xb - 12;
    const unsigned short* W = isGi ? Wih : Whh;
    float* C = isGi ? gi : gh;

    // ---- stage A tile (fp32 -> bf16, m_z built on the fly for gi path) ----
    {
        const int r  = tid >> 2;          // row 0..63
        const int fc = tid & 3;           // 128-col chunk
        const int b  = yb * 64 + r;
        const float* cs = colp + b * Ff;
        const float* mf = m_fix + b * Ff;
        const float azv = isGi ? a_z[b * Nn + Zi] : 0.f;
        const unsigned sw = ((unsigned)(r & 7)) << 4;
#pragma unroll
        for (int w = 0; w < 16; ++w) {
            int ff = fc * 128 + w * 8;
            float4 c0 = *(const float4*)(cs + ff);
            float4 c1 = *(const float4*)(cs + ff + 4);
            float v0, v1, v2, v3, v4, v5, v6, v7;
            if (isGi) {
                float4 m0 = *(const float4*)(mf + ff);
                float4 m1 = *(const float4*)(mf + ff + 4);
                v0 = m0.x + azv * c0.x; v1 = m0.y + azv * c0.y;
                v2 = m0.z + azv * c0.z; v3 = m0.w + azv * c0.w;
                v4 = m1.x + azv * c1.x; v5 = m1.y + azv * c1.y;
                v6 = m1.z + azv * c1.z; v7 = m1.w + azv * c1.w;
            } else {
                v0 = c0.x; v1 = c0.y; v2 = c0.z; v3 = c0.w;
                v4 = c1.x; v5 = c1.y; v6 = c1.z; v7 = c1.w;
            }
            uint4 pk;
            pk.x = (unsigned)f2bf(v0) | ((unsigned)f2bf(v1) << 16);
            pk.y = (unsigned)f2bf(v2) | ((unsigned)f2bf(v3) << 16);
            pk.z = (unsigned)f2bf(v4) | ((unsigned)f2bf(v5) << 16);
            pk.w = (unsigned)f2bf(v6) | ((unsigned)f2bf(v7) << 16);
            unsigned byte = ((unsigned)(r * 1024 + ff * 2)) ^ sw;
            *(uint4*)((char*)Ab + byte) = pk;
        }
    }

    stage_gates(W, nb, 0, &Wb[0][0], tid);
    __syncthreads();

    const int wid  = tid >> 6;
    const int lane = tid & 63;
    const int mh = wid >> 1;
    const int nh = wid & 1;
    const int lr = lane & 15;
    const int lk = lane >> 4;

    facc acc[2][4];
#pragma unroll
    for (int ms = 0; ms < 2; ++ms)
#pragma unroll
        for (int nt = 0; nt < 4; ++nt)
            acc[ms][nt] = (facc){0.f, 0.f, 0.f, 0.f};

#pragma unroll 1
    for (int k0 = 0; k0 < 16; ++k0) {
        if (k0 < 15) stage_gates(W, nb, k0 + 1, &Wb[(k0 + 1) & 1][0], tid);
        const char* Wc = (const char*)&Wb[k0 & 1][0];
        const int kk = k0 * 32 + lk * 8;
        bfrag a0, a1;
        {
            int row = mh * 32 + lr;
            unsigned byte = ((unsigned)(row * 1024 + kk * 2)) ^ (((unsigned)(row & 7)) << 4);
            a0 = *(const bfrag*)((const char*)Ab + byte);
            row += 16;
            byte = ((unsigned)(row * 1024 + kk * 2)) ^ (((unsigned)(row & 7)) << 4);
            a1 = *(const bfrag*)((const char*)Ab + byte);
        }
#pragma unroll
        for (int nt = 0; nt < 4; ++nt) {
            int g = nh * 64 + nt * 16 + lr;
            bfrag bf_ = *(const bfrag*)(Wc + (((unsigned)(g * 64 + lk * 16)) ^ (((unsigned)(g & 3)) << 4)));
            acc[0][nt] = __builtin_amdgcn_mfma_f32_16x16x32_bf16(a0, bf_, acc[0][nt], 0, 0, 0);
            acc[1][nt] = __builtin_amdgcn_mfma_f32_16x16x32_bf16(a1, bf_, acc[1][nt], 0, 0, 0);
        }
        __syncthreads();
    }

    // ---- epilogue: direct fp32 stores ----
#pragma unroll
    for (int nt = 0; nt < 4; ++nt) {
        int n = nb * 128 + nh * 64 + nt * 16 + lr;
#pragma unroll
        for (int ms = 0; ms < 2; ++ms) {
#pragma unroll
            for (int reg = 0; reg < 4; ++reg) {
                int row = yb * 64 + mh * 32 + ms * 16 + lk * 4 + reg;
                C[row * G3 + n] = acc[ms][nt][reg];
            }
        }
    }
}

// ---------------------------------------------------------------------------
// GRU pointwise: col = (1-z)*n + z*col
// ---------------------------------------------------------------------------
__global__ void gru_kernel(const float* __restrict__ gi, const float* __restrict__ gh,
                           float* __restrict__ col) {
    int idx = blockIdx.x * 256 + threadIdx.x;
    int b = idx >> 9, f = idx & 511;
    const float* gib = gi + b * G3;
    const float* ghb = gh + b * G3;
    float ir = gib[f], iz = gib[Ff + f], in = gib[2 * Ff + f];
    float hr = ghb[f], hz = ghb[Ff + f], hn = ghb[2 * Ff + f];
    float r = 1.f / (1.f + expf(-(ir + hr)));
    float z = 1.f / (1.f + expf(-(iz + hz)));
    float n = tanhf(in + r * hn);
    float h = col[idx];
    col[idx] = (1.f - z) * n + z * h;
}

// ---------------------------------------------------------------------------
extern "C" void kernel_launch(void* const* d_in, const int* in_sizes, int n_in,
                              void* d_out, int out_size, void* d_ws, size_t ws_size,
                              hipStream_t stream) {
    const float* nf    = (const float*)d_in[0];
    const float* W1    = (const float*)d_in[1];
    const float* b1    = (const float*)d_in[2];
    const float* W2    = (const float*)d_in[3];
    const float* b2    = (const float*)d_in[4];
    const float* w_out = (const float*)d_in[5];
    const float* b_out = (const float*)d_in[6];
    const float* W_ih  = (const float*)d_in[7];
    const float* W_hh  = (const float*)d_in[8];

    float* adj = (float*)d_out;                 // (B, 11, 11)
    float* col = adj + Bsz * Nn * Nn;           // (B, 512)

    float* ws    = (float*)d_ws;
    float* a_z   = ws;                          // B*11 (16384 slot)
    float* m_fix = ws + 16384;                  // B*512
    float* gi    = m_fix + Bsz * Ff;            // B*1536
    float* gh    = gi + Bsz * G3;               // B*1536
    unsigned short* W1bf  = (unsigned short*)(gh + Bsz * G3);   // 512*512
    unsigned short* W2bf  = W1bf + Ff * Ff;
    unsigned short* Wihbf = W2bf + Ff * Ff;                     // 1536*512
    unsigned short* Whhbf = Wihbf + G3 * Ff;

    init_col_kernel<<<(Bsz * Ff) / 256, 256, 0, stream>>>(nf, col);
    convert_bf16_kernel<<<(Ff * Ff) / 256, 256, 0, stream>>>(W1, W1bf);
    convert_bf16_kernel<<<(Ff * Ff) / 256, 256, 0, stream>>>(W2, W2bf);
    convert_bf16_kernel<<<(G3 * Ff) / 256, 256, 0, stream>>>(W_ih, Wihbf);
    convert_bf16_kernel<<<(G3 * Ff) / 256, 256, 0, stream>>>(W_hh, Whhbf);

    for (int t = 0; t < 3; ++t) {
        if (t == 0)
            link_mfma_kernel<<<66 * 16, 512, 0, stream>>>(nf, col, W1bf, b1, W2bf, b2,
                                                          w_out, b_out, adj, 0);
        else
            link_mfma_kernel<<<11 * 16, 512, 0, stream>>>(nf, col, W1bf, b1, W2bf, b2,
                                                          w_out, b_out, adj, 1);
        softmax_az_kernel<<<Bsz / 256, 256, 0, stream>>>(adj, a_z);
        mfix_kernel<<<(Bsz * Ff) / 256, 256, 0, stream>>>(nf, a_z, m_fix);

        for (int s = 0; s < 3; ++s) {
            gates_kernel<<<dim3(24, 16), 256, 0, stream>>>(m_fix, a_z, col,
                                                           Wihbf, Whhbf, gi, gh);
            gru_kernel<<<(Bsz * Ff) / 256, 256, 0, stream>>>(gi, gh, col);
        }
    }
}